// Round 3
// baseline (595.457 us; speedup 1.0000x reference)
//
#include <hip/hip_runtime.h>
#include <hip/hip_bf16.h>
#include <cstdint>
#include <cstddef>

#define BS   4
#define NN   2048
#define NH   2
#define FIN  768
#define FOUT 768
#define NEG_SLOPE 0.2f

typedef __attribute__((ext_vector_type(8))) short short8;
typedef __attribute__((ext_vector_type(4))) float float4v;

static __device__ __forceinline__ float bits2f(unsigned short u) {
    union { unsigned int i; float f; } v; v.i = ((unsigned int)u) << 16; return v.f;
}
// RNE fp32 -> bf16 bits
static __device__ __forceinline__ unsigned short f2bits(float f) {
    union { float f; unsigned int i; } v; v.f = f;
    unsigned int x = v.i;
    unsigned int r = x + 0x7fffu + ((x >> 16) & 1u);
    return (unsigned short)(r >> 16);
}

// ---------------------------------------------------------------------------
// K-1: runtime dtype detection.
//  flags[0] = 1 if float arrays are fp32 (else bf16)  [round-2 evidence: fp32]
//  flags[1] = 1 if adjacency is int8/bool (else int32)
// ---------------------------------------------------------------------------
__global__ __launch_bounds__(256) void k_detect(
    const unsigned short* __restrict__ h_raw,
    const unsigned char* __restrict__ adj_raw,
    int* __restrict__ flags)
{
    __shared__ int cnt_bf16, cnt_adj8;
    int t = threadIdx.x;
    if (t == 0) { cnt_bf16 = 0; cnt_adj8 = 0; }
    __syncthreads();
    unsigned short u = h_raw[t];
    int e = (u >> 7) & 0xFF;
    int ok = (e >= 118 && e <= 134) ? 1 : 0;   // bf16 N(0,1): ~99% pass; fp32 halves: ~53%
    int nz = 0;
    #pragma unroll
    for (int r = 0; r < 16; ++r) {
        int idx = t * 16 + r;
        if ((idx & 3) != 0 && adj_raw[idx] != 0) nz++;
    }
    atomicAdd(&cnt_bf16, ok);
    atomicAdd(&cnt_adj8, nz);
    __syncthreads();
    if (t == 0) {
        flags[0] = (cnt_bf16 < 200) ? 1 : 0;
        flags[1] = (cnt_adj8 > 16) ? 1 : 0;
    }
}

// ---------------------------------------------------------------------------
// K0a: h -> bf16
// ---------------------------------------------------------------------------
__global__ __launch_bounds__(256) void k_prep_h(
    const void* __restrict__ hr, unsigned short* __restrict__ hi,
    const int* __restrict__ flags, int n)
{
    bool isf = flags[0] != 0;
    int base = (blockIdx.x * 256 + threadIdx.x) * 4;
    if (base >= n) return;
    #pragma unroll
    for (int r = 0; r < 4; ++r) {
        int idx = base + r;
        float x = isf ? ((const float*)hr)[idx]
                      : bits2f(((const unsigned short*)hr)[idx]);
        hi[idx] = f2bits(x);
    }
}

// ---------------------------------------------------------------------------
// K0b: w[h][f][o] -> wt[h][o][f]  (transpose, bf16)
// ---------------------------------------------------------------------------
__global__ __launch_bounds__(256) void k_prep_w(
    const void* __restrict__ wr, unsigned short* __restrict__ wth,
    const int* __restrict__ flags)
{
    bool isf = flags[0] != 0;
    __shared__ float tile[32][33];
    int h  = blockIdx.z;
    int f0 = blockIdx.x * 32;
    int o0 = blockIdx.y * 32;
    int tx = threadIdx.x, ty = threadIdx.y;   // 32 x 8
    #pragma unroll
    for (int r = 0; r < 4; ++r) {
        int fl = ty * 4 + r;
        size_t idx = (size_t)h * FIN * FOUT + (size_t)(f0 + fl) * FOUT + (o0 + tx);
        tile[fl][tx] = isf ? ((const float*)wr)[idx]
                           : bits2f(((const unsigned short*)wr)[idx]);
    }
    __syncthreads();
    #pragma unroll
    for (int r = 0; r < 4; ++r) {
        int ol = ty * 4 + r;
        size_t oidx = (size_t)h * FOUT * FIN + (size_t)(o0 + ol) * FIN + (f0 + tx);
        wth[oidx] = f2bits(tile[tx][ol]);
    }
}

// ---------------------------------------------------------------------------
// K0c: a_src, a_dst, bias -> fp32
// ---------------------------------------------------------------------------
__global__ __launch_bounds__(256) void k_prep_vec(
    const void* __restrict__ asr, const void* __restrict__ adr,
    const void* __restrict__ br,
    float* __restrict__ asf, float* __restrict__ adf, float* __restrict__ bf,
    const int* __restrict__ flags)
{
    bool isf = flags[0] != 0;
    int t = threadIdx.x;
    for (int i = t; i < NH * FOUT; i += 256) {
        asf[i] = isf ? ((const float*)asr)[i] : bits2f(((const unsigned short*)asr)[i]);
        adf[i] = isf ? ((const float*)adr)[i] : bits2f(((const unsigned short*)adr)[i]);
    }
    for (int i = t; i < FOUT; i += 256) {
        bf[i] = isf ? ((const float*)br)[i] : bits2f(((const unsigned short*)br)[i]);
    }
}

// ---------------------------------------------------------------------------
// K0d: adj (int32 or int8) -> u8 keep-mask with diagonal baked in
// ---------------------------------------------------------------------------
__global__ __launch_bounds__(256) void k_prep_adj(
    const void* __restrict__ ar, unsigned char* __restrict__ mask,
    const int* __restrict__ flags, int n)
{
    bool is8 = flags[1] != 0;
    int base = (blockIdx.x * 256 + threadIdx.x) * 4;
    if (base >= n) return;
    #pragma unroll
    for (int r = 0; r < 4; ++r) {
        int idx = base + r;
        int v = is8 ? (int)((const unsigned char*)ar)[idx]
                    : ((const int*)ar)[idx];
        int row = (idx >> 11) & (NN - 1);
        int col = idx & (NN - 1);
        mask[idx] = (v != 0 || row == col) ? 1 : 0;
    }
}

// ---------------------------------------------------------------------------
// GEMM geometry: 128x128 tile, BK=32, 4 waves, 4x4 16x16x32 MFMA per wave.
// ---------------------------------------------------------------------------
#define BM 128
#define BN 128
#define BK 32
#define LSTR 40

// K1: hpT[bh][o][n] = sum_f h[b][n][f]*w[h][f][o]
__global__ __launch_bounds__(256) void k_gemm_hw(
    const unsigned short* __restrict__ hh,
    const unsigned short* __restrict__ wh,
    unsigned short* __restrict__ hpT)
{
    int ib = blockIdx.z;                      // bh
    int b  = ib / NH, hd = ib % NH;
    int i0 = blockIdx.x * BM;
    int o0 = blockIdx.y * BN;
    const unsigned short* A  = hh + (size_t)b  * NN * FIN;
    const unsigned short* Bt = wh + (size_t)hd * FOUT * FIN;
    unsigned short*       C  = hpT + (size_t)ib * FOUT * NN;

    __shared__ __align__(16) unsigned short As[BM * LSTR];
    __shared__ __align__(16) unsigned short Bs[BN * LSTR];

    int t = threadIdx.x;
    int lane = t & 63, wave = t >> 6;
    int wm = (wave & 1) * 64, wn = (wave >> 1) * 64;
    int lm = lane & 15, quad = lane >> 4;
    int row2 = t >> 2, col16 = t & 3;

    float4v acc[4][4] = {};

    for (int k0 = 0; k0 < FIN; k0 += BK) {
        __syncthreads();
        #pragma unroll
        for (int p = 0; p < 2; ++p) {
            int r = p * 64 + row2;
            *(uint4*)&As[r * LSTR + col16 * 8] =
                *(const uint4*)(A  + (size_t)(i0 + r) * FIN + k0 + col16 * 8);
            *(uint4*)&Bs[r * LSTR + col16 * 8] =
                *(const uint4*)(Bt + (size_t)(o0 + r) * FIN + k0 + col16 * 8);
        }
        __syncthreads();
        short8 fa[4], fb[4];
        #pragma unroll
        for (int mt = 0; mt < 4; ++mt)
            fa[mt] = *(const short8*)&As[(wm + mt * 16 + lm) * LSTR + quad * 8];
        #pragma unroll
        for (int nt = 0; nt < 4; ++nt)
            fb[nt] = *(const short8*)&Bs[(wn + nt * 16 + lm) * LSTR + quad * 8];
        #pragma unroll
        for (int mt = 0; mt < 4; ++mt)
            #pragma unroll
            for (int nt = 0; nt < 4; ++nt)
                acc[mt][nt] = __builtin_amdgcn_mfma_f32_16x16x32_bf16(
                    fa[mt], fb[nt], acc[mt][nt], 0, 0, 0);
    }

    // D: row(m=node)=quad*4+reg, col(n=o)=lm  ->  hpT[o][node..node+3]
    #pragma unroll
    for (int mt = 0; mt < 4; ++mt) {
        #pragma unroll
        for (int nt = 0; nt < 4; ++nt) {
            int node = i0 + wm + mt * 16 + quad * 4;
            int o    = o0 + wn + nt * 16 + lm;
            ushort4 v;
            v.x = f2bits(acc[mt][nt][0]);
            v.y = f2bits(acc[mt][nt][1]);
            v.z = f2bits(acc[mt][nt][2]);
            v.w = f2bits(acc[mt][nt][3]);
            *(ushort4*)&C[(size_t)o * NN + node] = v;
        }
    }
}

// ---------------------------------------------------------------------------
// K2: attn_src/dst[bh][n] = sum_o tanh(hp[n][o]) * a[h][o]
// ---------------------------------------------------------------------------
__global__ __launch_bounds__(256) void k_attn_vec(
    const unsigned short* __restrict__ hpT,
    const float* __restrict__ asf, const float* __restrict__ adf,
    float* __restrict__ attn_src, float* __restrict__ attn_dst)
{
    int bh = blockIdx.y, hd = bh % NH;
    int n = blockIdx.x * 256 + threadIdx.x;
    __shared__ float s_as[FOUT], s_ad[FOUT];
    for (int o = threadIdx.x; o < FOUT; o += 256) {
        s_as[o] = asf[hd * FOUT + o];
        s_ad[o] = adf[hd * FOUT + o];
    }
    __syncthreads();
    const unsigned short* hp = hpT + (size_t)bh * FOUT * NN;
    float as = 0.f, ad = 0.f;
    for (int o = 0; o < FOUT; ++o) {
        float tv = tanhf(bits2f(hp[(size_t)o * NN + n]));
        as += tv * s_as[o];
        ad += tv * s_ad[o];
    }
    attn_src[bh * NN + n] = as;
    attn_dst[bh * NN + n] = ad;
}

// ---------------------------------------------------------------------------
// K3: per (bh,i): masked leaky-relu scores, softmax, write P row (bf16)
// ---------------------------------------------------------------------------
__global__ __launch_bounds__(256) void k_softmax_p(
    const float* __restrict__ attn_src, const float* __restrict__ attn_dst,
    const unsigned char* __restrict__ mask,
    unsigned short* __restrict__ P)
{
    int blk = blockIdx.x;                     // bh*NN + i
    int i  = blk & (NN - 1);
    int bh = blk >> 11;
    int b  = bh / NH;
    int t  = threadIdx.x;
    int lane = t & 63, wave = t >> 6;

    float src = attn_src[bh * NN + i];
    const unsigned char* mrow = mask + ((size_t)b * NN + i) * NN;
    const float* drow = attn_dst + (size_t)bh * NN;

    int j0 = t * 8;
    float s[8];
    float lmax = -1e30f;
    #pragma unroll
    for (int r = 0; r < 8; ++r) {
        int j = j0 + r;
        float sc = src + drow[j];
        sc = sc >= 0.f ? sc : NEG_SLOPE * sc;
        s[r] = (mrow[j] != 0) ? sc : -1e30f;
        lmax = fmaxf(lmax, s[r]);
    }
    __shared__ float redm[4], reds[4];
    #pragma unroll
    for (int off = 32; off > 0; off >>= 1)
        lmax = fmaxf(lmax, __shfl_xor(lmax, off));
    if (lane == 0) redm[wave] = lmax;
    __syncthreads();
    float m = fmaxf(fmaxf(redm[0], redm[1]), fmaxf(redm[2], redm[3]));

    float p[8];
    float lsum = 0.f;
    #pragma unroll
    for (int r = 0; r < 8; ++r) {
        p[r] = __expf(s[r] - m);
        lsum += p[r];
    }
    #pragma unroll
    for (int off = 32; off > 0; off >>= 1)
        lsum += __shfl_xor(lsum, off);
    if (lane == 0) reds[wave] = lsum;
    __syncthreads();
    float inv = 1.0f / (reds[0] + reds[1] + reds[2] + reds[3]);

    uint4 pw;
    pw.x = ((unsigned int)f2bits(p[1] * inv) << 16) | f2bits(p[0] * inv);
    pw.y = ((unsigned int)f2bits(p[3] * inv) << 16) | f2bits(p[2] * inv);
    pw.z = ((unsigned int)f2bits(p[5] * inv) << 16) | f2bits(p[4] * inv);
    pw.w = ((unsigned int)f2bits(p[7] * inv) << 16) | f2bits(p[6] * inv);
    *(uint4*)&P[(size_t)blk * NN + j0] = pw;
}

// ---------------------------------------------------------------------------
// K4: out[bh][i][o] = sum_j P[i][j]*hpT[o][j] + bias[o]
//     Output dtype follows input mode: fp32 when flags[0], else bf16.
// ---------------------------------------------------------------------------
__global__ __launch_bounds__(256) void k_gemm_out(
    const unsigned short* __restrict__ P,
    const unsigned short* __restrict__ hpT,
    const float* __restrict__ bf,
    void* __restrict__ outp, const int* __restrict__ flags)
{
    bool isf = flags[0] != 0;
    int ib = blockIdx.z;
    int i0 = blockIdx.x * BM;
    int o0 = blockIdx.y * BN;
    const unsigned short* A  = P   + (size_t)ib * NN * NN;
    const unsigned short* Bt = hpT + (size_t)ib * FOUT * NN;

    __shared__ __align__(16) unsigned short As[BM * LSTR];
    __shared__ __align__(16) unsigned short Bs[BN * LSTR];

    int t = threadIdx.x;
    int lane = t & 63, wave = t >> 6;
    int wm = (wave & 1) * 64, wn = (wave >> 1) * 64;
    int lm = lane & 15, quad = lane >> 4;
    int row2 = t >> 2, col16 = t & 3;

    float4v acc[4][4] = {};

    for (int k0 = 0; k0 < NN; k0 += BK) {
        __syncthreads();
        #pragma unroll
        for (int p = 0; p < 2; ++p) {
            int r = p * 64 + row2;
            *(uint4*)&As[r * LSTR + col16 * 8] =
                *(const uint4*)(A  + (size_t)(i0 + r) * NN + k0 + col16 * 8);
            *(uint4*)&Bs[r * LSTR + col16 * 8] =
                *(const uint4*)(Bt + (size_t)(o0 + r) * NN + k0 + col16 * 8);
        }
        __syncthreads();
        short8 fa[4], fb[4];
        #pragma unroll
        for (int mt = 0; mt < 4; ++mt)
            fa[mt] = *(const short8*)&As[(wm + mt * 16 + lm) * LSTR + quad * 8];
        #pragma unroll
        for (int nt = 0; nt < 4; ++nt)
            fb[nt] = *(const short8*)&Bs[(wn + nt * 16 + lm) * LSTR + quad * 8];
        #pragma unroll
        for (int mt = 0; mt < 4; ++mt)
            #pragma unroll
            for (int nt = 0; nt < 4; ++nt)
                acc[mt][nt] = __builtin_amdgcn_mfma_f32_16x16x32_bf16(
                    fa[mt], fb[nt], acc[mt][nt], 0, 0, 0);
    }

    if (isf) {
        float* C = (float*)outp + (size_t)ib * NN * FOUT;
        #pragma unroll
        for (int nt = 0; nt < 4; ++nt) {
            int o = o0 + wn + nt * 16 + lm;
            float bv = bf[o];
            #pragma unroll
            for (int mt = 0; mt < 4; ++mt) {
                int i = i0 + wm + mt * 16 + quad * 4;
                #pragma unroll
                for (int r = 0; r < 4; ++r)
                    C[(size_t)(i + r) * FOUT + o] = acc[mt][nt][r] + bv;
            }
        }
    } else {
        unsigned short* C = (unsigned short*)outp + (size_t)ib * NN * FOUT;
        #pragma unroll
        for (int nt = 0; nt < 4; ++nt) {
            int o = o0 + wn + nt * 16 + lm;
            float bv = bf[o];
            #pragma unroll
            for (int mt = 0; mt < 4; ++mt) {
                int i = i0 + wm + mt * 16 + quad * 4;
                #pragma unroll
                for (int r = 0; r < 4; ++r)
                    C[(size_t)(i + r) * FOUT + o] = f2bits(acc[mt][nt][r] + bv);
            }
        }
    }
}

// ---------------------------------------------------------------------------
extern "C" void kernel_launch(void* const* d_in, const int* in_sizes, int n_in,
                              void* d_out, int out_size, void* d_ws, size_t ws_size,
                              hipStream_t stream)
{
    const void* h_raw   = d_in[0];
    const void* adj_raw = d_in[1];
    const void* w_raw   = d_in[2];
    const void* as_raw  = d_in[3];
    const void* ad_raw  = d_in[4];
    const void* b_raw   = d_in[5];

    char* ws = (char*)d_ws;
    size_t off = 0;
    int*   flags = (int*)(ws + off);            off += 256;
    unsigned short* hpT = (unsigned short*)(ws + off); off += (size_t)BS * NH * FOUT * NN * 2;
    float* asr = (float*)(ws + off);            off += (size_t)BS * NH * NN * 4;
    float* ads = (float*)(ws + off);            off += (size_t)BS * NH * NN * 4;
    // union: {h_bf16, wt_bf16} live only until k_gemm_hw; P overlays after.
    size_t uoff = off;
    unsigned short* P    = (unsigned short*)(ws + uoff);
    unsigned short* h_bf = (unsigned short*)(ws + uoff); uoff += (size_t)BS * NN * FIN * 2;
    unsigned short* wt_b = (unsigned short*)(ws + uoff); uoff += (size_t)NH * FOUT * FIN * 2;
    off += (size_t)BS * NH * NN * NN * 2;       // P dominates the union
    float* asf = (float*)(ws + off);            off += (size_t)NH * FOUT * 4;
    float* adf = (float*)(ws + off);            off += (size_t)NH * FOUT * 4;
    float* bff = (float*)(ws + off);            off += 4096;
    unsigned char* mask = (unsigned char*)(ws + off); off += (size_t)BS * NN * NN;

    int n_h   = BS * NN * FIN;
    int n_adj = BS * NN * NN;

    k_detect<<<1, 256, 0, stream>>>((const unsigned short*)h_raw,
                                    (const unsigned char*)adj_raw, flags);
    k_prep_h<<<n_h / 1024, 256, 0, stream>>>(h_raw, h_bf, flags, n_h);
    k_prep_w<<<dim3(FIN / 32, FOUT / 32, NH), dim3(32, 8), 0, stream>>>(
        w_raw, wt_b, flags);
    k_prep_vec<<<1, 256, 0, stream>>>(as_raw, ad_raw, b_raw, asf, adf, bff, flags);
    k_prep_adj<<<n_adj / 1024, 256, 0, stream>>>(adj_raw, mask, flags, n_adj);
    k_gemm_hw<<<dim3(NN / BM, FOUT / BN, BS * NH), 256, 0, stream>>>(h_bf, wt_b, hpT);
    k_attn_vec<<<dim3(NN / 256, BS * NH), 256, 0, stream>>>(hpT, asf, adf, asr, ads);
    k_softmax_p<<<dim3(BS * NH * NN), 256, 0, stream>>>(asr, ads, mask, P);
    k_gemm_out<<<dim3(NN / BM, FOUT / BN, BS * NH), 256, 0, stream>>>(
        P, hpT, bff, d_out, flags);
}

// Round 4
// 336.014 us; speedup vs baseline: 1.7721x; 1.7721x over previous
//
#include <hip/hip_runtime.h>
#include <hip/hip_bf16.h>
#include <cstdint>
#include <cstddef>

#define BS   4
#define NN   2048
#define NH   2
#define FIN  768
#define FOUT 768
#define NEG_SLOPE 0.2f

typedef __attribute__((ext_vector_type(8))) short short8;
typedef __attribute__((ext_vector_type(4))) float float4v;

static __device__ __forceinline__ float bits2f(unsigned short u) {
    union { unsigned int i; float f; } v; v.i = ((unsigned int)u) << 16; return v.f;
}
// RNE fp32 -> bf16 bits
static __device__ __forceinline__ unsigned short f2bits(float f) {
    union { float f; unsigned int i; } v; v.f = f;
    unsigned int x = v.i;
    unsigned int r = x + 0x7fffu + ((x >> 16) & 1u);
    return (unsigned short)(r >> 16);
}
// fast tanh via hardware exp; rel err ~1e-6, safe for |x| -> clamp +-20
static __device__ __forceinline__ float fast_tanh(float x) {
    float xc = fminf(fmaxf(x, -20.f), 20.f);
    float e = __expf(2.f * xc);
    return (e - 1.f) / (e + 1.f);
}

// ---------------------------------------------------------------------------
// K-1: runtime dtype detection.
//  flags[0] = 1 if float arrays are fp32 (else bf16)  [measured: fp32]
//  flags[1] = 1 if adjacency is int8/bool (else int32)
// ---------------------------------------------------------------------------
__global__ __launch_bounds__(256) void k_detect(
    const unsigned short* __restrict__ h_raw,
    const unsigned char* __restrict__ adj_raw,
    int* __restrict__ flags)
{
    __shared__ int cnt_bf16, cnt_adj8;
    int t = threadIdx.x;
    if (t == 0) { cnt_bf16 = 0; cnt_adj8 = 0; }
    __syncthreads();
    unsigned short u = h_raw[t];
    int e = (u >> 7) & 0xFF;
    int ok = (e >= 118 && e <= 134) ? 1 : 0;
    int nz = 0;
    #pragma unroll
    for (int r = 0; r < 16; ++r) {
        int idx = t * 16 + r;
        if ((idx & 3) != 0 && adj_raw[idx] != 0) nz++;
    }
    atomicAdd(&cnt_bf16, ok);
    atomicAdd(&cnt_adj8, nz);
    __syncthreads();
    if (t == 0) {
        flags[0] = (cnt_bf16 < 200) ? 1 : 0;
        flags[1] = (cnt_adj8 > 16) ? 1 : 0;
    }
}

// ---------------------------------------------------------------------------
// K0z: zero the attn accumulators (ws is poisoned 0xAA each call)
// ---------------------------------------------------------------------------
__global__ __launch_bounds__(256) void k_zero(float* __restrict__ p, int n) {
    int i = blockIdx.x * 256 + threadIdx.x;
    if (i < n) p[i] = 0.f;
}

// ---------------------------------------------------------------------------
// K0a: h -> bf16
// ---------------------------------------------------------------------------
__global__ __launch_bounds__(256) void k_prep_h(
    const void* __restrict__ hr, unsigned short* __restrict__ hi,
    const int* __restrict__ flags, int n)
{
    bool isf = flags[0] != 0;
    int base = (blockIdx.x * 256 + threadIdx.x) * 4;
    if (base >= n) return;
    #pragma unroll
    for (int r = 0; r < 4; ++r) {
        int idx = base + r;
        float x = isf ? ((const float*)hr)[idx]
                      : bits2f(((const unsigned short*)hr)[idx]);
        hi[idx] = f2bits(x);
    }
}

// ---------------------------------------------------------------------------
// K0b: w[h][f][o] -> wt[h][o][f]  (transpose, bf16)
// ---------------------------------------------------------------------------
__global__ __launch_bounds__(256) void k_prep_w(
    const void* __restrict__ wr, unsigned short* __restrict__ wth,
    const int* __restrict__ flags)
{
    bool isf = flags[0] != 0;
    __shared__ float tile[32][33];
    int h  = blockIdx.z;
    int f0 = blockIdx.x * 32;
    int o0 = blockIdx.y * 32;
    int tx = threadIdx.x, ty = threadIdx.y;   // 32 x 8
    #pragma unroll
    for (int r = 0; r < 4; ++r) {
        int fl = ty * 4 + r;
        size_t idx = (size_t)h * FIN * FOUT + (size_t)(f0 + fl) * FOUT + (o0 + tx);
        tile[fl][tx] = isf ? ((const float*)wr)[idx]
                           : bits2f(((const unsigned short*)wr)[idx]);
    }
    __syncthreads();
    #pragma unroll
    for (int r = 0; r < 4; ++r) {
        int ol = ty * 4 + r;
        size_t oidx = (size_t)h * FOUT * FIN + (size_t)(o0 + ol) * FIN + (f0 + tx);
        wth[oidx] = f2bits(tile[tx][ol]);
    }
}

// ---------------------------------------------------------------------------
// K0c: a_src, a_dst, bias -> fp32
// ---------------------------------------------------------------------------
__global__ __launch_bounds__(256) void k_prep_vec(
    const void* __restrict__ asr, const void* __restrict__ adr,
    const void* __restrict__ br,
    float* __restrict__ asf, float* __restrict__ adf, float* __restrict__ bf,
    const int* __restrict__ flags)
{
    bool isf = flags[0] != 0;
    int t = threadIdx.x;
    for (int i = t; i < NH * FOUT; i += 256) {
        asf[i] = isf ? ((const float*)asr)[i] : bits2f(((const unsigned short*)asr)[i]);
        adf[i] = isf ? ((const float*)adr)[i] : bits2f(((const unsigned short*)adr)[i]);
    }
    for (int i = t; i < FOUT; i += 256) {
        bf[i] = isf ? ((const float*)br)[i] : bits2f(((const unsigned short*)br)[i]);
    }
}

// ---------------------------------------------------------------------------
// K0d: adj (int32 or int8) -> u8 keep-mask with diagonal baked in
// ---------------------------------------------------------------------------
__global__ __launch_bounds__(256) void k_prep_adj(
    const void* __restrict__ ar, unsigned char* __restrict__ mask,
    const int* __restrict__ flags, int n)
{
    bool is8 = flags[1] != 0;
    int base = (blockIdx.x * 256 + threadIdx.x) * 4;
    if (base >= n) return;
    #pragma unroll
    for (int r = 0; r < 4; ++r) {
        int idx = base + r;
        int v = is8 ? (int)((const unsigned char*)ar)[idx]
                    : ((const int*)ar)[idx];
        int row = (idx >> 11) & (NN - 1);
        int col = idx & (NN - 1);
        mask[idx] = (v != 0 || row == col) ? 1 : 0;
    }
}

// ---------------------------------------------------------------------------
// GEMM geometry: 128x128 tile, BK=32, 4 waves, 4x4 16x16x32 MFMA per wave.
// ---------------------------------------------------------------------------
#define BM 128
#define BN 128
#define BK 32
#define LSTR 40

// K1: hpT[bh][o][n] = sum_f h[b][n][f]*w[h][f][o]
__global__ __launch_bounds__(256) void k_gemm_hw(
    const unsigned short* __restrict__ hh,
    const unsigned short* __restrict__ wh,
    unsigned short* __restrict__ hpT)
{
    int ib = blockIdx.z;                      // bh
    int b  = ib / NH, hd = ib % NH;
    int i0 = blockIdx.x * BM;
    int o0 = blockIdx.y * BN;
    const unsigned short* A  = hh + (size_t)b  * NN * FIN;
    const unsigned short* Bt = wh + (size_t)hd * FOUT * FIN;
    unsigned short*       C  = hpT + (size_t)ib * FOUT * NN;

    __shared__ __align__(16) unsigned short As[BM * LSTR];
    __shared__ __align__(16) unsigned short Bs[BN * LSTR];

    int t = threadIdx.x;
    int lane = t & 63, wave = t >> 6;
    int wm = (wave & 1) * 64, wn = (wave >> 1) * 64;
    int lm = lane & 15, quad = lane >> 4;
    int row2 = t >> 2, col16 = t & 3;

    float4v acc[4][4] = {};

    for (int k0 = 0; k0 < FIN; k0 += BK) {
        __syncthreads();
        #pragma unroll
        for (int p = 0; p < 2; ++p) {
            int r = p * 64 + row2;
            *(uint4*)&As[r * LSTR + col16 * 8] =
                *(const uint4*)(A  + (size_t)(i0 + r) * FIN + k0 + col16 * 8);
            *(uint4*)&Bs[r * LSTR + col16 * 8] =
                *(const uint4*)(Bt + (size_t)(o0 + r) * FIN + k0 + col16 * 8);
        }
        __syncthreads();
        short8 fa[4], fb[4];
        #pragma unroll
        for (int mt = 0; mt < 4; ++mt)
            fa[mt] = *(const short8*)&As[(wm + mt * 16 + lm) * LSTR + quad * 8];
        #pragma unroll
        for (int nt = 0; nt < 4; ++nt)
            fb[nt] = *(const short8*)&Bs[(wn + nt * 16 + lm) * LSTR + quad * 8];
        #pragma unroll
        for (int mt = 0; mt < 4; ++mt)
            #pragma unroll
            for (int nt = 0; nt < 4; ++nt)
                acc[mt][nt] = __builtin_amdgcn_mfma_f32_16x16x32_bf16(
                    fa[mt], fb[nt], acc[mt][nt], 0, 0, 0);
    }

    #pragma unroll
    for (int mt = 0; mt < 4; ++mt) {
        #pragma unroll
        for (int nt = 0; nt < 4; ++nt) {
            int node = i0 + wm + mt * 16 + quad * 4;
            int o    = o0 + wn + nt * 16 + lm;
            ushort4 v;
            v.x = f2bits(acc[mt][nt][0]);
            v.y = f2bits(acc[mt][nt][1]);
            v.z = f2bits(acc[mt][nt][2]);
            v.w = f2bits(acc[mt][nt][3]);
            *(ushort4*)&C[(size_t)o * NN + node] = v;
        }
    }
}

// ---------------------------------------------------------------------------
// K2: attn partials. Grid (NN/256, BS*NH, OSPLIT): each block covers 64 o's,
// fp32 atomicAdd into attn_src/attn_dst (zeroed by k_zero).
// ---------------------------------------------------------------------------
#define OSPLIT 12
#define OCHUNK (FOUT / OSPLIT)    // 64
__global__ __launch_bounds__(256) void k_attn_vec(
    const unsigned short* __restrict__ hpT,
    const float* __restrict__ asf, const float* __restrict__ adf,
    float* __restrict__ attn_src, float* __restrict__ attn_dst)
{
    int bh = blockIdx.y, hd = bh % NH;
    int oc = blockIdx.z * OCHUNK;
    int n = blockIdx.x * 256 + threadIdx.x;
    __shared__ float s_as[OCHUNK], s_ad[OCHUNK];
    if (threadIdx.x < OCHUNK) {
        s_as[threadIdx.x] = asf[hd * FOUT + oc + threadIdx.x];
        s_ad[threadIdx.x] = adf[hd * FOUT + oc + threadIdx.x];
    }
    __syncthreads();
    const unsigned short* hp = hpT + (size_t)bh * FOUT * NN + (size_t)oc * NN;
    float as = 0.f, ad = 0.f;
    #pragma unroll 4
    for (int o = 0; o < OCHUNK; ++o) {
        float tv = fast_tanh(bits2f(hp[(size_t)o * NN + n]));
        as += tv * s_as[o];
        ad += tv * s_ad[o];
    }
    atomicAdd(&attn_src[bh * NN + n], as);
    atomicAdd(&attn_dst[bh * NN + n], ad);
}

// ---------------------------------------------------------------------------
// K3: per (bh,i): masked leaky-relu scores, softmax, write P row (bf16)
// ---------------------------------------------------------------------------
__global__ __launch_bounds__(256) void k_softmax_p(
    const float* __restrict__ attn_src, const float* __restrict__ attn_dst,
    const unsigned char* __restrict__ mask,
    unsigned short* __restrict__ P)
{
    int blk = blockIdx.x;                     // bh*NN + i
    int i  = blk & (NN - 1);
    int bh = blk >> 11;
    int b  = bh / NH;
    int t  = threadIdx.x;
    int lane = t & 63, wave = t >> 6;

    float src = attn_src[bh * NN + i];
    const unsigned char* mrow = mask + ((size_t)b * NN + i) * NN;
    const float* drow = attn_dst + (size_t)bh * NN;

    int j0 = t * 8;
    float s[8];
    float lmax = -1e30f;
    #pragma unroll
    for (int r = 0; r < 8; ++r) {
        int j = j0 + r;
        float sc = src + drow[j];
        sc = sc >= 0.f ? sc : NEG_SLOPE * sc;
        s[r] = (mrow[j] != 0) ? sc : -1e30f;
        lmax = fmaxf(lmax, s[r]);
    }
    __shared__ float redm[4], reds[4];
    #pragma unroll
    for (int off = 32; off > 0; off >>= 1)
        lmax = fmaxf(lmax, __shfl_xor(lmax, off));
    if (lane == 0) redm[wave] = lmax;
    __syncthreads();
    float m = fmaxf(fmaxf(redm[0], redm[1]), fmaxf(redm[2], redm[3]));

    float p[8];
    float lsum = 0.f;
    #pragma unroll
    for (int r = 0; r < 8; ++r) {
        p[r] = __expf(s[r] - m);
        lsum += p[r];
    }
    #pragma unroll
    for (int off = 32; off > 0; off >>= 1)
        lsum += __shfl_xor(lsum, off);
    if (lane == 0) reds[wave] = lsum;
    __syncthreads();
    float inv = 1.0f / (reds[0] + reds[1] + reds[2] + reds[3]);

    uint4 pw;
    pw.x = ((unsigned int)f2bits(p[1] * inv) << 16) | f2bits(p[0] * inv);
    pw.y = ((unsigned int)f2bits(p[3] * inv) << 16) | f2bits(p[2] * inv);
    pw.z = ((unsigned int)f2bits(p[5] * inv) << 16) | f2bits(p[4] * inv);
    pw.w = ((unsigned int)f2bits(p[7] * inv) << 16) | f2bits(p[6] * inv);
    *(uint4*)&P[(size_t)blk * NN + j0] = pw;
}

// ---------------------------------------------------------------------------
// K4: out[bh][i][o] = sum_j P[i][j]*hpT[o][j] + bias[o]
// ---------------------------------------------------------------------------
__global__ __launch_bounds__(256) void k_gemm_out(
    const unsigned short* __restrict__ P,
    const unsigned short* __restrict__ hpT,
    const float* __restrict__ bf,
    void* __restrict__ outp, const int* __restrict__ flags)
{
    bool isf = flags[0] != 0;
    int ib = blockIdx.z;
    int i0 = blockIdx.x * BM;
    int o0 = blockIdx.y * BN;
    const unsigned short* A  = P   + (size_t)ib * NN * NN;
    const unsigned short* Bt = hpT + (size_t)ib * FOUT * NN;

    __shared__ __align__(16) unsigned short As[BM * LSTR];
    __shared__ __align__(16) unsigned short Bs[BN * LSTR];

    int t = threadIdx.x;
    int lane = t & 63, wave = t >> 6;
    int wm = (wave & 1) * 64, wn = (wave >> 1) * 64;
    int lm = lane & 15, quad = lane >> 4;
    int row2 = t >> 2, col16 = t & 3;

    float4v acc[4][4] = {};

    for (int k0 = 0; k0 < NN; k0 += BK) {
        __syncthreads();
        #pragma unroll
        for (int p = 0; p < 2; ++p) {
            int r = p * 64 + row2;
            *(uint4*)&As[r * LSTR + col16 * 8] =
                *(const uint4*)(A  + (size_t)(i0 + r) * NN + k0 + col16 * 8);
            *(uint4*)&Bs[r * LSTR + col16 * 8] =
                *(const uint4*)(Bt + (size_t)(o0 + r) * NN + k0 + col16 * 8);
        }
        __syncthreads();
        short8 fa[4], fb[4];
        #pragma unroll
        for (int mt = 0; mt < 4; ++mt)
            fa[mt] = *(const short8*)&As[(wm + mt * 16 + lm) * LSTR + quad * 8];
        #pragma unroll
        for (int nt = 0; nt < 4; ++nt)
            fb[nt] = *(const short8*)&Bs[(wn + nt * 16 + lm) * LSTR + quad * 8];
        #pragma unroll
        for (int mt = 0; mt < 4; ++mt)
            #pragma unroll
            for (int nt = 0; nt < 4; ++nt)
                acc[mt][nt] = __builtin_amdgcn_mfma_f32_16x16x32_bf16(
                    fa[mt], fb[nt], acc[mt][nt], 0, 0, 0);
    }

    if (isf) {
        float* C = (float*)outp + (size_t)ib * NN * FOUT;
        #pragma unroll
        for (int nt = 0; nt < 4; ++nt) {
            int o = o0 + wn + nt * 16 + lm;
            float bv = bf[o];
            #pragma unroll
            for (int mt = 0; mt < 4; ++mt) {
                int i = i0 + wm + mt * 16 + quad * 4;
                #pragma unroll
                for (int r = 0; r < 4; ++r)
                    C[(size_t)(i + r) * FOUT + o] = acc[mt][nt][r] + bv;
            }
        }
    } else {
        unsigned short* C = (unsigned short*)outp + (size_t)ib * NN * FOUT;
        #pragma unroll
        for (int nt = 0; nt < 4; ++nt) {
            int o = o0 + wn + nt * 16 + lm;
            float bv = bf[o];
            #pragma unroll
            for (int mt = 0; mt < 4; ++mt) {
                int i = i0 + wm + mt * 16 + quad * 4;
                #pragma unroll
                for (int r = 0; r < 4; ++r)
                    C[(size_t)(i + r) * FOUT + o] = f2bits(acc[mt][nt][r] + bv);
            }
        }
    }
}

// ---------------------------------------------------------------------------
extern "C" void kernel_launch(void* const* d_in, const int* in_sizes, int n_in,
                              void* d_out, int out_size, void* d_ws, size_t ws_size,
                              hipStream_t stream)
{
    const void* h_raw   = d_in[0];
    const void* adj_raw = d_in[1];
    const void* w_raw   = d_in[2];
    const void* as_raw  = d_in[3];
    const void* ad_raw  = d_in[4];
    const void* b_raw   = d_in[5];

    char* ws = (char*)d_ws;
    size_t off = 0;
    int*   flags = (int*)(ws + off);            off += 256;
    unsigned short* hpT = (unsigned short*)(ws + off); off += (size_t)BS * NH * FOUT * NN * 2;
    float* asr = (float*)(ws + off);            off += (size_t)BS * NH * NN * 4;
    float* ads = (float*)(ws + off);            off += (size_t)BS * NH * NN * 4;
    // union: {h_bf16, wt_bf16} live only until k_gemm_hw; P overlays after.
    size_t uoff = off;
    unsigned short* P    = (unsigned short*)(ws + uoff);
    unsigned short* h_bf = (unsigned short*)(ws + uoff); uoff += (size_t)BS * NN * FIN * 2;
    unsigned short* wt_b = (unsigned short*)(ws + uoff); uoff += (size_t)NH * FOUT * FIN * 2;
    off += (size_t)BS * NH * NN * NN * 2;       // P dominates the union
    float* asf = (float*)(ws + off);            off += (size_t)NH * FOUT * 4;
    float* adf = (float*)(ws + off);            off += (size_t)NH * FOUT * 4;
    float* bff = (float*)(ws + off);            off += 4096;
    unsigned char* mask = (unsigned char*)(ws + off); off += (size_t)BS * NN * NN;

    int n_h   = BS * NN * FIN;
    int n_adj = BS * NN * NN;
    int n_attn = 2 * BS * NH * NN;              // asr and ads are contiguous

    k_detect<<<1, 256, 0, stream>>>((const unsigned short*)h_raw,
                                    (const unsigned char*)adj_raw, flags);
    k_zero<<<(n_attn + 255) / 256, 256, 0, stream>>>(asr, n_attn);
    k_prep_h<<<n_h / 1024, 256, 0, stream>>>(h_raw, h_bf, flags, n_h);
    k_prep_w<<<dim3(FIN / 32, FOUT / 32, NH), dim3(32, 8), 0, stream>>>(
        w_raw, wt_b, flags);
    k_prep_vec<<<1, 256, 0, stream>>>(as_raw, ad_raw, b_raw, asf, adf, bff, flags);
    k_prep_adj<<<n_adj / 1024, 256, 0, stream>>>(adj_raw, mask, flags, n_adj);
    k_gemm_hw<<<dim3(NN / BM, FOUT / BN, BS * NH), 256, 0, stream>>>(h_bf, wt_b, hpT);
    k_attn_vec<<<dim3(NN / 256, BS * NH, OSPLIT), 256, 0, stream>>>(
        hpT, asf, adf, asr, ads);
    k_softmax_p<<<dim3(BS * NH * NN), 256, 0, stream>>>(asr, ads, mask, P);
    k_gemm_out<<<dim3(NN / BM, FOUT / BN, BS * NH), 256, 0, stream>>>(
        P, hpT, bff, d_out, flags);
}

// Round 5
// 296.943 us; speedup vs baseline: 2.0053x; 1.1316x over previous
//
#include <hip/hip_runtime.h>
#include <hip/hip_bf16.h>
#include <cstdint>
#include <cstddef>

#define BS   4
#define NN   2048
#define NH   2
#define FIN  768
#define FOUT 768
#define NEG_SLOPE 0.2f

typedef __attribute__((ext_vector_type(8))) short short8;
typedef __attribute__((ext_vector_type(4))) float float4v;

static __device__ __forceinline__ float bits2f(unsigned short u) {
    union { unsigned int i; float f; } v; v.i = ((unsigned int)u) << 16; return v.f;
}
// RNE fp32 -> bf16 bits
static __device__ __forceinline__ unsigned short f2bits(float f) {
    union { float f; unsigned int i; } v; v.f = f;
    unsigned int x = v.i;
    unsigned int r = x + 0x7fffu + ((x >> 16) & 1u);
    return (unsigned short)(r >> 16);
}
// fast tanh via hardware exp; rel err ~1e-6
static __device__ __forceinline__ float fast_tanh(float x) {
    float xc = fminf(fmaxf(x, -20.f), 20.f);
    float e = __expf(2.f * xc);
    return (e - 1.f) / (e + 1.f);
}
// async global->LDS, 16B per lane; lds base must be wave-uniform
static __device__ __forceinline__ void async_copy16(void* lds, const void* g) {
    __builtin_amdgcn_global_load_lds(
        (const __attribute__((address_space(1))) unsigned int*)g,
        (__attribute__((address_space(3))) unsigned int*)lds, 16, 0, 0);
}

// Per-block dtype detection (uniform across block; all waves sample lanes 0..63)
// fp32 inputs: only odd u16 halves have sane exponents (~34/64 pass);
// bf16 inputs: ~64/64 pass.
static __device__ __forceinline__ bool detect_isf32(const unsigned short* h_raw) {
    unsigned short u = h_raw[threadIdx.x & 63];
    int e = (u >> 7) & 0xFF;
    unsigned long long m = __ballot(e >= 118 && e <= 134);
    return __popcll(m) < 48;
}
// int32 adj: bytes at offset %4!=0 are all zero; u8 adj: mostly nonzero
static __device__ __forceinline__ bool detect_adj8(const unsigned char* adj_raw) {
    int l = threadIdx.x & 63;
    unsigned char v = (unsigned char)(adj_raw[l * 4 + 1] | adj_raw[l * 4 + 2] |
                                      adj_raw[l * 4 + 3]);
    unsigned long long m = __ballot(v != 0);
    return __popcll(m) > 8;
}

// ---------------------------------------------------------------------------
// K_misc: blocks [0,128): zero attn accumulators; block 128: a_src/a_dst/bias->f32
// ---------------------------------------------------------------------------
__global__ __launch_bounds__(256) void k_misc(
    float* __restrict__ attn_acc,             // 2*BS*NH*NN floats (asr then ads)
    const void* __restrict__ as_raw, const void* __restrict__ ad_raw,
    const void* __restrict__ b_raw, const unsigned short* __restrict__ h_raw,
    float* __restrict__ asf, float* __restrict__ adf, float* __restrict__ bff)
{
    const int nzb = (2 * BS * NH * NN) / 256;     // 128
    int bi = blockIdx.x;
    if (bi < nzb) {
        attn_acc[bi * 256 + threadIdx.x] = 0.f;
        return;
    }
    bool isf = detect_isf32(h_raw);
    int t = threadIdx.x;
    for (int i = t; i < NH * FOUT; i += 256) {
        asf[i] = isf ? ((const float*)as_raw)[i] : bits2f(((const unsigned short*)as_raw)[i]);
        adf[i] = isf ? ((const float*)ad_raw)[i] : bits2f(((const unsigned short*)ad_raw)[i]);
    }
    for (int i = t; i < FOUT; i += 256)
        bff[i] = isf ? ((const float*)b_raw)[i] : bits2f(((const unsigned short*)b_raw)[i]);
}

// ---------------------------------------------------------------------------
// K_prep_h: h -> bf16 (8 elems/thread, vectorized)
// ---------------------------------------------------------------------------
__global__ __launch_bounds__(256) void k_prep_h(
    const void* __restrict__ hr, unsigned short* __restrict__ dst, int n)
{
    bool isf = detect_isf32((const unsigned short*)hr);
    int base = (blockIdx.x * 256 + threadIdx.x) * 8;
    if (base >= n) return;
    if (isf) {
        float4 f0 = *((const float4*)((const float*)hr + base));
        float4 f1 = *((const float4*)((const float*)hr + base + 4));
        unsigned short v[8] = { f2bits(f0.x), f2bits(f0.y), f2bits(f0.z), f2bits(f0.w),
                                f2bits(f1.x), f2bits(f1.y), f2bits(f1.z), f2bits(f1.w) };
        *(uint4*)(dst + base) = *(const uint4*)v;
    } else {
        *(uint4*)(dst + base) = *(const uint4*)((const unsigned short*)hr + base);
    }
}

// ---------------------------------------------------------------------------
// K_prep_w: w[h][f][o] -> wt[h][o][f]  (transpose, bf16)
// ---------------------------------------------------------------------------
__global__ __launch_bounds__(256) void k_prep_w(
    const void* __restrict__ wr, unsigned short* __restrict__ wth,
    const unsigned short* __restrict__ h_raw)
{
    bool isf = detect_isf32(h_raw);
    __shared__ float tile[32][33];
    int h  = blockIdx.z;
    int f0 = blockIdx.x * 32;
    int o0 = blockIdx.y * 32;
    int tx = threadIdx.x, ty = threadIdx.y;   // 32 x 8
    #pragma unroll
    for (int r = 0; r < 4; ++r) {
        int fl = ty * 4 + r;
        size_t idx = (size_t)h * FIN * FOUT + (size_t)(f0 + fl) * FOUT + (o0 + tx);
        tile[fl][tx] = isf ? ((const float*)wr)[idx]
                           : bits2f(((const unsigned short*)wr)[idx]);
    }
    __syncthreads();
    #pragma unroll
    for (int r = 0; r < 4; ++r) {
        int ol = ty * 4 + r;
        size_t oidx = (size_t)h * FOUT * FIN + (size_t)(o0 + ol) * FIN + (f0 + tx);
        wth[oidx] = f2bits(tile[tx][ol]);
    }
}

// ---------------------------------------------------------------------------
// GEMM geometry: 128x128 tile, BK=32, 4 waves, 4x4 16x16x32 MFMA per wave.
// LDS unpadded [row][32] for global_load_lds; chunk-XOR swizzle kills bank
// conflicts: LDS slot s of row L holds global chunk (s ^ ((L>>1)&3)).
// ---------------------------------------------------------------------------
#define BM 128
#define BN 128
#define BK 32

// K1: hpT[bh][o][n] = sum_f h[b][n][f]*w[h][f][o]; fused attn_src/dst epilogue
__global__ __launch_bounds__(256) void k_gemm_hw(
    const unsigned short* __restrict__ hh,
    const unsigned short* __restrict__ wh,
    unsigned short* __restrict__ hpT,
    const float* __restrict__ asf, const float* __restrict__ adf,
    float* __restrict__ attn_src, float* __restrict__ attn_dst)
{
    int ib = blockIdx.z;                      // bh
    int b  = ib / NH, hd = ib % NH;
    int i0 = blockIdx.x * BM;
    int o0 = blockIdx.y * BN;
    const unsigned short* A  = hh + (size_t)b  * NN * FIN;
    const unsigned short* Bt = wh + (size_t)hd * FOUT * FIN;
    unsigned short*       C  = hpT + (size_t)ib * FOUT * NN;

    __shared__ __align__(16) unsigned short As[BM * BK];
    __shared__ __align__(16) unsigned short Bs[BN * BK];

    int t = threadIdx.x;
    int lane = t & 63, wave = t >> 6;
    int wm = (wave & 1) * 64, wn = (wave >> 1) * 64;
    int lm = lane & 15, quad = lane >> 4;
    int rr = lane >> 2;                       // staging: local row 0..15
    int cc = (lane & 3) ^ ((rr >> 1) & 3);    // staging: swizzled chunk
    int sA = (lm >> 1) & 3;                   // read-side swizzle

    float4v acc[4][4] = {};

    for (int k0 = 0; k0 < FIN; k0 += BK) {
        __syncthreads();
        #pragma unroll
        for (int p = 0; p < 2; ++p) {
            int r0 = wave * 32 + p * 16;
            async_copy16(&As[r0 * BK], A  + (size_t)(i0 + r0 + rr) * FIN + k0 + cc * 8);
            async_copy16(&Bs[r0 * BK], Bt + (size_t)(o0 + r0 + rr) * FIN + k0 + cc * 8);
        }
        __syncthreads();
        short8 fa[4], fb[4];
        #pragma unroll
        for (int mt = 0; mt < 4; ++mt)
            fa[mt] = *(const short8*)&As[(wm + mt * 16 + lm) * BK + ((quad ^ sA) * 8)];
        #pragma unroll
        for (int nt = 0; nt < 4; ++nt)
            fb[nt] = *(const short8*)&Bs[(wn + nt * 16 + lm) * BK + ((quad ^ sA) * 8)];
        #pragma unroll
        for (int mt = 0; mt < 4; ++mt)
            #pragma unroll
            for (int nt = 0; nt < 4; ++nt)
                acc[mt][nt] = __builtin_amdgcn_mfma_f32_16x16x32_bf16(
                    fa[mt], fb[nt], acc[mt][nt], 0, 0, 0);
    }

    // epilogue: store hpT + fused tanh-dot partials for attn_src/dst
    float asv[4], adv[4];
    #pragma unroll
    for (int nt = 0; nt < 4; ++nt) {
        int o = o0 + wn + nt * 16 + lm;
        asv[nt] = asf[hd * FOUT + o];
        adv[nt] = adf[hd * FOUT + o];
    }
    #pragma unroll
    for (int mt = 0; mt < 4; ++mt) {
        float ps[4] = {0.f, 0.f, 0.f, 0.f};
        float pd[4] = {0.f, 0.f, 0.f, 0.f};
        #pragma unroll
        for (int nt = 0; nt < 4; ++nt) {
            int node = i0 + wm + mt * 16 + quad * 4;
            int o    = o0 + wn + nt * 16 + lm;
            ushort4 v;
            v.x = f2bits(acc[mt][nt][0]);
            v.y = f2bits(acc[mt][nt][1]);
            v.z = f2bits(acc[mt][nt][2]);
            v.w = f2bits(acc[mt][nt][3]);
            *(ushort4*)&C[(size_t)o * NN + node] = v;
            #pragma unroll
            for (int r = 0; r < 4; ++r) {
                float tv = fast_tanh(acc[mt][nt][r]);
                ps[r] += tv * asv[nt];
                pd[r] += tv * adv[nt];
            }
        }
        #pragma unroll
        for (int r = 0; r < 4; ++r) {
            float s = ps[r], d = pd[r];
            #pragma unroll
            for (int off = 1; off <= 8; off <<= 1) {
                s += __shfl_xor(s, off);
                d += __shfl_xor(d, off);
            }
            if (lm == 0) {
                int node = i0 + wm + mt * 16 + quad * 4 + r;
                atomicAdd(&attn_src[ib * NN + node], s);
                atomicAdd(&attn_dst[ib * NN + node], d);
            }
        }
    }
}

// ---------------------------------------------------------------------------
// K3: per (b,i): read adj row once, softmax for both heads, write P rows
// ---------------------------------------------------------------------------
__global__ __launch_bounds__(256) void k_softmax_p(
    const float* __restrict__ attn_src, const float* __restrict__ attn_dst,
    const void* __restrict__ adj_raw,
    unsigned short* __restrict__ P)
{
    int blk = blockIdx.x;                     // b*NN + i
    int i = blk & (NN - 1);
    int b = blk >> 11;
    bool is8 = detect_adj8((const unsigned char*)adj_raw);
    int t = threadIdx.x;
    int lane = t & 63, wave = t >> 6;
    int j0 = t * 8;

    bool keep[8];
    if (is8) {
        const unsigned char* arow = (const unsigned char*)adj_raw + ((size_t)b * NN + i) * NN;
        uint2 v = *(const uint2*)(arow + j0);
        #pragma unroll
        for (int r = 0; r < 8; ++r) {
            unsigned int w = (r < 4) ? v.x : v.y;
            keep[r] = ((w >> ((r & 3) * 8)) & 0xFFu) != 0;
        }
    } else {
        const int* arow = (const int*)adj_raw + ((size_t)b * NN + i) * NN;
        int4 v0 = *(const int4*)(arow + j0);
        int4 v1 = *(const int4*)(arow + j0 + 4);
        keep[0] = v0.x != 0; keep[1] = v0.y != 0; keep[2] = v0.z != 0; keep[3] = v0.w != 0;
        keep[4] = v1.x != 0; keep[5] = v1.y != 0; keep[6] = v1.z != 0; keep[7] = v1.w != 0;
    }
    #pragma unroll
    for (int r = 0; r < 8; ++r) keep[r] = keep[r] || (j0 + r == i);

    __shared__ float redm[4], reds[4];
    for (int hh = 0; hh < NH; ++hh) {
        int bh = b * NH + hh;
        float src = attn_src[bh * NN + i];
        const float* drow = attn_dst + (size_t)bh * NN;
        float4 d0 = *(const float4*)(drow + j0);
        float4 d1 = *(const float4*)(drow + j0 + 4);
        float dj[8] = { d0.x, d0.y, d0.z, d0.w, d1.x, d1.y, d1.z, d1.w };

        float s[8];
        float lmax = -1e30f;
        #pragma unroll
        for (int r = 0; r < 8; ++r) {
            float sc = src + dj[r];
            sc = sc >= 0.f ? sc : NEG_SLOPE * sc;
            s[r] = keep[r] ? sc : -1e30f;
            lmax = fmaxf(lmax, s[r]);
        }
        __syncthreads();                       // protect redm/reds reuse across heads
        #pragma unroll
        for (int off = 32; off > 0; off >>= 1)
            lmax = fmaxf(lmax, __shfl_xor(lmax, off));
        if (lane == 0) redm[wave] = lmax;
        __syncthreads();
        float m = fmaxf(fmaxf(redm[0], redm[1]), fmaxf(redm[2], redm[3]));

        float p[8];
        float lsum = 0.f;
        #pragma unroll
        for (int r = 0; r < 8; ++r) {
            p[r] = __expf(s[r] - m);
            lsum += p[r];
        }
        #pragma unroll
        for (int off = 32; off > 0; off >>= 1)
            lsum += __shfl_xor(lsum, off);
        if (lane == 0) reds[wave] = lsum;
        __syncthreads();
        float inv = 1.0f / (reds[0] + reds[1] + reds[2] + reds[3]);

        uint4 pw;
        pw.x = ((unsigned int)f2bits(p[1] * inv) << 16) | f2bits(p[0] * inv);
        pw.y = ((unsigned int)f2bits(p[3] * inv) << 16) | f2bits(p[2] * inv);
        pw.z = ((unsigned int)f2bits(p[5] * inv) << 16) | f2bits(p[4] * inv);
        pw.w = ((unsigned int)f2bits(p[7] * inv) << 16) | f2bits(p[6] * inv);
        *(uint4*)&P[((size_t)bh * NN + i) * NN + j0] = pw;
    }
}

// ---------------------------------------------------------------------------
// K4: out[bh][i][o] = sum_j P[i][j]*hpT[o][j] + bias[o]
// ---------------------------------------------------------------------------
__global__ __launch_bounds__(256) void k_gemm_out(
    const unsigned short* __restrict__ P,
    const unsigned short* __restrict__ hpT,
    const float* __restrict__ bf,
    void* __restrict__ outp, const unsigned short* __restrict__ h_raw)
{
    bool isf = detect_isf32(h_raw);
    int ib = blockIdx.z;
    int i0 = blockIdx.x * BM;
    int o0 = blockIdx.y * BN;
    const unsigned short* A  = P   + (size_t)ib * NN * NN;
    const unsigned short* Bt = hpT + (size_t)ib * FOUT * NN;

    __shared__ __align__(16) unsigned short As[BM * BK];
    __shared__ __align__(16) unsigned short Bs[BN * BK];

    int t = threadIdx.x;
    int lane = t & 63, wave = t >> 6;
    int wm = (wave & 1) * 64, wn = (wave >> 1) * 64;
    int lm = lane & 15, quad = lane >> 4;
    int rr = lane >> 2;
    int cc = (lane & 3) ^ ((rr >> 1) & 3);
    int sA = (lm >> 1) & 3;

    float4v acc[4][4] = {};

    for (int k0 = 0; k0 < NN; k0 += BK) {
        __syncthreads();
        #pragma unroll
        for (int p = 0; p < 2; ++p) {
            int r0 = wave * 32 + p * 16;
            async_copy16(&As[r0 * BK], A  + (size_t)(i0 + r0 + rr) * NN + k0 + cc * 8);
            async_copy16(&Bs[r0 * BK], Bt + (size_t)(o0 + r0 + rr) * NN + k0 + cc * 8);
        }
        __syncthreads();
        short8 fa[4], fb[4];
        #pragma unroll
        for (int mt = 0; mt < 4; ++mt)
            fa[mt] = *(const short8*)&As[(wm + mt * 16 + lm) * BK + ((quad ^ sA) * 8)];
        #pragma unroll
        for (int nt = 0; nt < 4; ++nt)
            fb[nt] = *(const short8*)&Bs[(wn + nt * 16 + lm) * BK + ((quad ^ sA) * 8)];
        #pragma unroll
        for (int mt = 0; mt < 4; ++mt)
            #pragma unroll
            for (int nt = 0; nt < 4; ++nt)
                acc[mt][nt] = __builtin_amdgcn_mfma_f32_16x16x32_bf16(
                    fa[mt], fb[nt], acc[mt][nt], 0, 0, 0);
    }

    if (isf) {
        float* C = (float*)outp + (size_t)ib * NN * FOUT;
        #pragma unroll
        for (int nt = 0; nt < 4; ++nt) {
            int o = o0 + wn + nt * 16 + lm;
            float bv = bf[o];
            #pragma unroll
            for (int mt = 0; mt < 4; ++mt) {
                int i = i0 + wm + mt * 16 + quad * 4;
                #pragma unroll
                for (int r = 0; r < 4; ++r)
                    C[(size_t)(i + r) * FOUT + o] = acc[mt][nt][r] + bv;
            }
        }
    } else {
        unsigned short* C = (unsigned short*)outp + (size_t)ib * NN * FOUT;
        #pragma unroll
        for (int nt = 0; nt < 4; ++nt) {
            int o = o0 + wn + nt * 16 + lm;
            float bv = bf[o];
            #pragma unroll
            for (int mt = 0; mt < 4; ++mt) {
                int i = i0 + wm + mt * 16 + quad * 4;
                #pragma unroll
                for (int r = 0; r < 4; ++r)
                    C[(size_t)(i + r) * FOUT + o] = f2bits(acc[mt][nt][r] + bv);
            }
        }
    }
}

// ---------------------------------------------------------------------------
extern "C" void kernel_launch(void* const* d_in, const int* in_sizes, int n_in,
                              void* d_out, int out_size, void* d_ws, size_t ws_size,
                              hipStream_t stream)
{
    const void* h_raw   = d_in[0];
    const void* adj_raw = d_in[1];
    const void* w_raw   = d_in[2];
    const void* as_raw  = d_in[3];
    const void* ad_raw  = d_in[4];
    const void* b_raw   = d_in[5];

    char* ws = (char*)d_ws;
    size_t off = 0;
    unsigned short* hpT = (unsigned short*)(ws + off); off += (size_t)BS * NH * FOUT * NN * 2;
    float* asr = (float*)(ws + off);            off += (size_t)BS * NH * NN * 4;
    float* ads = (float*)(ws + off);            off += (size_t)BS * NH * NN * 4;
    // union: {h_bf16, wt_bf16} live only until k_gemm_hw; P overlays after.
    size_t uoff = off;
    unsigned short* P    = (unsigned short*)(ws + uoff);
    unsigned short* h_bf = (unsigned short*)(ws + uoff); uoff += (size_t)BS * NN * FIN * 2;
    unsigned short* wt_b = (unsigned short*)(ws + uoff); uoff += (size_t)NH * FOUT * FIN * 2;
    off += (size_t)BS * NH * NN * NN * 2;       // P dominates the union
    float* asf = (float*)(ws + off);            off += (size_t)NH * FOUT * 4;
    float* adf = (float*)(ws + off);            off += (size_t)NH * FOUT * 4;
    float* bff = (float*)(ws + off);            off += 4096;

    int n_h = BS * NN * FIN;

    k_misc<<<(2 * BS * NH * NN) / 256 + 1, 256, 0, stream>>>(
        asr, as_raw, ad_raw, b_raw, (const unsigned short*)h_raw, asf, adf, bff);
    k_prep_h<<<n_h / (256 * 8), 256, 0, stream>>>(h_raw, h_bf, n_h);
    k_prep_w<<<dim3(FIN / 32, FOUT / 32, NH), dim3(32, 8), 0, stream>>>(
        w_raw, wt_b, (const unsigned short*)h_raw);
    k_gemm_hw<<<dim3(NN / BM, FOUT / BN, BS * NH), 256, 0, stream>>>(
        h_bf, wt_b, hpT, asf, adf, asr, ads);
    k_softmax_p<<<dim3(BS * NN), 256, 0, stream>>>(asr, ads, adj_raw, P);
    k_gemm_out<<<dim3(NN / BM, FOUT / BN, BS * NH), 256, 0, stream>>>(
        P, hpT, bff, d_out, (const unsigned short*)h_raw);
}